// Round 5
// baseline (323.769 us; speedup 1.0000x reference)
//
#include <hip/hip_runtime.h>

typedef __bf16 bf16_t;
typedef __bf16 bf16x4 __attribute__((ext_vector_type(4)));
typedef __bf16 bf16x8 __attribute__((ext_vector_type(8)));
typedef short s16x4 __attribute__((ext_vector_type(4)));
typedef float f32x4 __attribute__((ext_vector_type(4)));

#define BN_EPS 1e-3f

#define GLOAD_LDS16(g, l) \
  __builtin_amdgcn_global_load_lds((const __attribute__((address_space(1))) void*)(g), \
                                   (__attribute__((address_space(3))) void*)(l), 16, 0, 0)

// ---------------- fp32 -> bf16 elementwise convert (8 elems/thread) ----------------
__global__ __launch_bounds__(256) void cvt_f32_bf16(
    const float* __restrict__ in, bf16_t* __restrict__ out, long n)
{
  long i = ((long)blockIdx.x * 256 + threadIdx.x) * 8;
  if (i + 8 > n) return;
  f32x4 a = *(const f32x4*)(in + i);
  f32x4 b = *(const f32x4*)(in + i + 4);
  bf16x8 o;
  o[0] = (bf16_t)a[0]; o[1] = (bf16_t)a[1]; o[2] = (bf16_t)a[2]; o[3] = (bf16_t)a[3];
  o[4] = (bf16_t)b[0]; o[5] = (bf16_t)b[1]; o[6] = (bf16_t)b[2]; o[7] = (bf16_t)b[3];
  *(bf16x8*)(out + i) = o;
}

// ---------------- weight transpose fp32 in[R][C] -> bf16 out[C][R] ----------------
__global__ __launch_bounds__(256) void transpose_f32_bf16(
    const float* __restrict__ in, bf16_t* __restrict__ out, int R, int C)
{
  __shared__ bf16_t t[32][33];
  int bx = blockIdx.x * 32, by = blockIdx.y * 32;
  int tx = threadIdx.x, ty = threadIdx.y;
#pragma unroll
  for (int i = 0; i < 32; i += 8)
    t[ty + i][tx] = (bf16_t)in[(long)(by + ty + i) * C + (bx + tx)];
  __syncthreads();
#pragma unroll
  for (int i = 0; i < 32; i += 8)
    out[(long)(bx + ty + i) * R + (by + tx)] = t[tx][ty + i];
}

// ------- Wkv split-transpose: fp32 [256][640] -> WkT[128][256], WvT[512][256] bf16 -------
__global__ __launch_bounds__(256) void wkv_split_transpose(
    const float* __restrict__ in, bf16_t* __restrict__ outK, bf16_t* __restrict__ outV)
{
  __shared__ bf16_t t[32][33];
  int bx = blockIdx.x * 32, by = blockIdx.y * 32;   // bx over 640 cols, by over 256 rows
  int tx = threadIdx.x, ty = threadIdx.y;
#pragma unroll
  for (int i = 0; i < 32; i += 8)
    t[ty + i][tx] = (bf16_t)in[(long)(by + ty + i) * 640 + (bx + tx)];
  __syncthreads();
#pragma unroll
  for (int i = 0; i < 32; i += 8) {
    int c = bx + ty + i;                 // kv channel 0..639
    int h = c / 80, r80 = c - h * 80;
    bf16_t v = t[tx][ty + i];
    if (r80 < 16)
      outK[(long)(h * 16 + r80) * 256 + (by + tx)] = v;
    else
      outV[(long)(h * 64 + (r80 - 16)) * 256 + (by + tx)] = v;
  }
}

// ---------------- fused GEMM + BN (+ scatter epilogues) ----------------
// R5: (a) register-hoisted K-loop: all 8 A-frags + 32 B-frags loaded (fully unrolled,
//     compile-time indices) BEFORE the MFMAs -> ~40 loads in flight vs ~3 at 44 VGPRs.
//     __launch_bounds__(256,2) caps VGPR at 256 (est ~190). R4 counters: MfmaUtil 3.7%,
//     VALU 7.7%, HBM 14% -> pure latency-bound, per-block 13k cyc == 40 serial ~900cyc misses.
//     MODE 2 (K=512) hoists in two K=256 chunks. Accumulation order unchanged.
// (b) MODE 3 grid -> 1D 4096 with bijective XCD decode: xcd=id&7, slot=id>>3,
//     ntile=xcd*64+(slot>>3), mtile=slot&7. Old grid (8m,512n) put the 8 m-blocks sharing
//     a B-tile on 8 DIFFERENT XCDs (XCD=linear%8=m) -> each XCD streamed ALL of xb (16MB):
//     FETCH 65.7MB vs 16.5 unique. New map: each XCD owns a contiguous 4096-col stripe
//     (2MB, fits 4MB XCD L2), m-blocks per n-tile temporally adjacent -> B read once.
// MODE 0: K   A=xb[32768][256], WkT[128][256] -> K[bh][4096][16]
// MODE 1: Q   A=xb (strided row gather), WqT[128][256] -> Q[bh][1024][16] (*0.25*log2e)
// MODE 2: PROJ A=outp[8192][512], WpT[512][512] -> d_out fp32 [8192][512]
// MODE 3: V^T A=WvT[512][256], B=xb -> Vt interleaved for attn's x32 PV MFMA:
//   elem (bh, key, dv) -> idx = bh<<18 | kb<<11 | qd<<9 | dv<<3 | j
template <int MODE>
__global__ __launch_bounds__(256, 2) void gemm_bn(
    const bf16_t* __restrict__ A, const bf16_t* __restrict__ Wt,
    const float* __restrict__ bias, const float* __restrict__ gamma,
    const float* __restrict__ beta, const float* __restrict__ mean,
    const float* __restrict__ var,
    bf16_t* __restrict__ out0, float* __restrict__ outf)
{
  constexpr int KTOT = (MODE == 2) ? 512 : 256;
  const int lane = threadIdx.x & 63;
  const int w = threadIdx.x >> 6;
  const int quad = lane >> 4, l15 = lane & 15;

  int m0, n0;
  if constexpr (MODE == 3) {
    int id = blockIdx.x;                 // 0..4095
    int xcd = id & 7, slot = id >> 3;    // slot 0..511
    int ntile = xcd * 64 + (slot >> 3);  // 0..511
    int mtile = slot & 7;                // 0..7
    m0 = mtile * 64 + w * 16;
    n0 = ntile * 64;
  } else {
    m0 = blockIdx.x * 64 + w * 16;
    n0 = blockIdx.y * 64;
  }

  int mrow = m0 + l15;
  int arow;
  if constexpr (MODE == 1) {
    int b = mrow >> 10, qp = mrow & 1023;
    arow = (b << 12) + ((qp >> 5) << 7) + ((qp & 31) << 1);
  } else {
    arow = mrow;
  }
  const bf16_t* ap = A + (long)arow * KTOT + quad * 8;
  const bf16_t* bp = Wt + (long)(n0 + l15) * KTOT + quad * 8;

  f32x4 acc[4] = {};
#pragma unroll
  for (int kc = 0; kc < KTOT / 256; kc++) {
    bf16x8 a[8];
    bf16x8 bfr[4][8];
#pragma unroll
    for (int ks = 0; ks < 8; ks++)
      a[ks] = *(const bf16x8*)(ap + kc * 256 + ks * 32);
#pragma unroll
    for (int nt = 0; nt < 4; nt++)
#pragma unroll
      for (int ks = 0; ks < 8; ks++)
        bfr[nt][ks] = *(const bf16x8*)(bp + (long)nt * 16 * KTOT + kc * 256 + ks * 32);
#pragma unroll
    for (int ks = 0; ks < 8; ks++)
#pragma unroll
      for (int nt = 0; nt < 4; nt++)
        acc[nt] = __builtin_amdgcn_mfma_f32_16x16x32_bf16(a[ks], bfr[nt][ks], acc[nt], 0, 0, 0);
  }

  if constexpr (MODE == 3) {
    // rows = V channels, cols = x rows. BN per ROW.
    float sB[4], tB[4], bB[4];
#pragma unroll
    for (int r = 0; r < 4; r++) {
      int ch = m0 + quad * 4 + r;                      // 0..511
      int c = (ch >> 6) * 80 + 16 + (ch & 63);         // kv param index
      sB[r] = gamma[c] / sqrtf(var[c] + BN_EPS);
      tB[r] = beta[c] - mean[c] * sB[r];
      bB[r] = bias[c];
    }
#pragma unroll
    for (int nt = 0; nt < 4; nt++) {
      int n = n0 + nt * 16 + l15;                      // x row
      int b = n >> 12, seq = n & 4095;
      int kb = seq >> 5, s32 = seq & 31;
      int qd = (s32 & 15) >> 2, j = (s32 >> 4) * 4 + (s32 & 3);
#pragma unroll
      for (int r = 0; r < 4; r++) {
        int ch = m0 + quad * 4 + r;
        float y = (acc[nt][r] + bB[r]) * sB[r] + tB[r];
        int h2 = ch >> 6, dv = ch & 63;
        out0[(((long)(b * 8 + h2)) << 18) + (kb << 11) + (qd << 9) + (dv << 3) + j] = (bf16_t)y;
      }
    }
    return;
  }

#pragma unroll
  for (int nt = 0; nt < 4; nt++) {
    int col = n0 + nt * 16 + l15;
    int cp;
    if constexpr (MODE == 0) cp = (col >> 4) * 80 + (col & 15);
    else cp = col;
    float s = gamma[cp] / sqrtf(var[cp] + BN_EPS);
    float t = beta[cp] - mean[cp] * s;
    float bia = bias[cp];
#pragma unroll
    for (int r = 0; r < 4; r++) {
      int grow = m0 + quad * 4 + r;
      float y = (acc[nt][r] + bia) * s + t;
      if constexpr (MODE == 0) {
        int h = col >> 4, d = col & 15;
        int b = grow >> 12, seq = grow & 4095;
        out0[((long)((b * 8 + h) * 4096 + seq)) * 16 + d] = (bf16_t)y;   // K [bh][seq][16]
      } else if constexpr (MODE == 1) {
        int h = col >> 4, d = col & 15;
        int b = grow >> 10, qp = grow & 1023;
        out0[((long)((b * 8 + h) * 1024 + qp)) * 16 + d] = (bf16_t)(y * 0.36067376f);
      } else {
        outf[(long)grow * 512 + col] = y;
      }
    }
  }
}

// ---------------- flash attention: all-x32 MFMA, 4-wave blocks, depth-2 counted vmcnt ----------------
// R4 (kept): QK^T/PV/lp all via native mfma_f32_16x16x32_bf16 (the CDNA3-compat _1k K=16 op
// measured 16.8 cyc/instr vs 4.85 for x32 at 2x FLOP). Q d=16 zero-padded to K=32; V written
// by gemm<3> in the (kb,quad,dv,j) interleave matching P's slot->key map; ones-row MFMA for lp.
// 4-wave blocks (16 q/wave), 40 KB LDS (4 bufs), grid 1024 -> 4 blocks/CU. Depth-2 pipeline:
// stage(t+2) after the barrier, counted vmcnt (w<2: 2, else 3), conflict-free 16B ds reads.
__global__ __launch_bounds__(256, 4) void attn_kernel(
    const bf16_t* __restrict__ Q, const bf16_t* __restrict__ K,
    const bf16_t* __restrict__ Vt, bf16_t* __restrict__ outp)
{
  const int tid = threadIdx.x;
  const int lane = tid & 63, w = tid >> 6;                // 4 waves
  const int quad = lane >> 4, l15 = lane & 15;
  const int bh = blockIdx.x & 63, qb = blockIdx.x >> 6;   // qb 0..15
  const int b = bh >> 3, h = bh & 7;
  const bf16_t* Qp = Q + (long)bh * 1024 * 16;
  const char* Kg = (const char*)(K + (long)bh * 4096 * 16);     // [key][16d], 32 B/row
  const char* Vg = (const char*)(Vt + ((long)bh << 18));        // interleaved, 512 KB/bh

  // K tile (64 keys): [d-half h][row] 16B slots: addr = h*1024 + row*16
  // V tile (64 keys): [kh][quad][dv] 16B slots: addr = kh*4096 + quad*1024 + dv*16
  __shared__ __align__(16) char Kl[4][2048];
  __shared__ __align__(16) char Vl[4][8192];

  const int q0 = qb * 64 + w * 16;
  // Q x32 B-frag: lane(quad,l15): k=quad*8+j -> d (quads 0,1 real, quads 2,3 zero)
  bf16x8 qB8;
  {
    bf16x8 qv = *(const bf16x8*)(Qp + (long)(q0 + l15) * 16 + (quad & 1) * 8);
    bf16x8 zq = {};
    qB8 = (quad < 2) ? qv : zq;
  }

  f32x4 O[4] = {};           // O^T frags: lane holds (q=l15, dv=dt*16+quad*4+r)
  f32x4 lpacc = {};          // ones-MFMA: every row = sum_k P[k][q=l15]
  const f32x4 zf = {0.f, 0.f, 0.f, 0.f};

  bf16x8 ones8;
#pragma unroll
  for (int i = 0; i < 8; i++) ones8[i] = (bf16_t)1.f;

  // staging sources
  const char* vsrc = Vg + (long)lane * 16;                // + t*8192 + chunk*1024
  const char* ksrc = Kg + (long)lane * 32 + (w - 2) * 16; // w>=2 only: K half (w-2)

  auto stage = [&](int t, int buf) {
    if (w < 2) {
#pragma unroll
      for (int c = 0; c < 2; c++)
        GLOAD_LDS16(vsrc + (long)t * 8192 + (w * 2 + c) * 1024, &Vl[buf][(w * 2 + c) * 1024]);
    } else {
#pragma unroll
      for (int c = 0; c < 2; c++)
        GLOAD_LDS16(vsrc + (long)t * 8192 + ((w - 2) * 2 + 4 + c) * 1024,
                    &Vl[buf][((w - 2) * 2 + 4 + c) * 1024]);
      GLOAD_LDS16(ksrc + (long)t * 2048, &Kl[buf][(w - 2) * 1024]);
    }
  };

  const int krow_off = (quad & 1) * 1024;   // quads 0,2 -> d-half 0; 1,3 -> half 1

  auto compute = [&](int buf) {
#pragma unroll
    for (int kh = 0; kh < 2; kh++) {
      bf16x8 k0 = *(const bf16x8*)(&Kl[buf][krow_off + (kh * 32 + l15) * 16]);
      bf16x8 k1 = *(const bf16x8*)(&Kl[buf][krow_off + (kh * 32 + 16 + l15) * 16]);
      f32x4 S0 = __builtin_amdgcn_mfma_f32_16x16x32_bf16(k0, qB8, zf, 0, 0, 0);
      f32x4 S1 = __builtin_amdgcn_mfma_f32_16x16x32_bf16(k1, qB8, zf, 0, 0, 0);
      bf16x8 pb;
      pb[0] = (bf16_t)__builtin_amdgcn_exp2f(S0[0]);
      pb[1] = (bf16_t)__builtin_amdgcn_exp2f(S0[1]);
      pb[2] = (bf16_t)__builtin_amdgcn_exp2f(S0[2]);
      pb[3] = (bf16_t)__builtin_amdgcn_exp2f(S0[3]);
      pb[4] = (bf16_t)__builtin_amdgcn_exp2f(S1[0]);
      pb[5] = (bf16_t)__builtin_amdgcn_exp2f(S1[1]);
      pb[6] = (bf16_t)__builtin_amdgcn_exp2f(S1[2]);
      pb[7] = (bf16_t)__builtin_amdgcn_exp2f(S1[3]);
      lpacc = __builtin_amdgcn_mfma_f32_16x16x32_bf16(ones8, pb, lpacc, 0, 0, 0);
#pragma unroll
      for (int dt = 0; dt < 4; dt++) {
        bf16x8 vA = *(const bf16x8*)(&Vl[buf][kh * 4096 + quad * 1024 + (dt * 16 + l15) * 16]);
        O[dt] = __builtin_amdgcn_mfma_f32_16x16x32_bf16(vA, pb, O[dt], 0, 0, 0);
      }
    }
  };

  stage(0, 0);
  stage(1, 1);
#pragma unroll 4
  for (int t = 0; t < 64; t++) {
    if (t < 63) {
      if (w < 2) asm volatile("s_waitcnt vmcnt(2)" ::: "memory");
      else       asm volatile("s_waitcnt vmcnt(3)" ::: "memory");
    } else {
      asm volatile("s_waitcnt vmcnt(0)" ::: "memory");
    }
    __builtin_amdgcn_s_barrier();        // all waves' tile-t loads retired -> tile t complete
    __builtin_amdgcn_sched_barrier(0);   // pin: no ds_read hoisted above the barrier
    if (t + 2 < 64) stage(t + 2, (t + 2) & 3);
    compute(t & 3);
  }

  // lpacc rows all equal the key-sum for q=l15
  float rl = __builtin_amdgcn_rcpf(lpacc[0]);
  int q = q0 + l15;
  long colq = q & 511;
  long rowbase = (long)b * 1024 + (long)h * 128 + (q >> 9);
#pragma unroll
  for (int dt = 0; dt < 4; dt++) {
#pragma unroll
    for (int r = 0; r < 4; r++) {
      int dv = dt * 16 + quad * 4 + r;
      float val = O[dt][r] * rl;
      float hs = val * fminf(fmaxf(val + 3.f, 0.f), 6.f) * (1.f / 6.f);
      outp[(rowbase + (long)dv * 2) * 512 + colq] = (bf16_t)hs;
    }
  }
}

extern "C" void kernel_launch(void* const* d_in, const int* in_sizes, int n_in,
                              void* d_out, int out_size, void* d_ws, size_t ws_size,
                              hipStream_t stream)
{
  const float* x    = (const float*)d_in[0];
  const float* Wkv  = (const float*)d_in[1];
  const float* bkv  = (const float*)d_in[2];
  const float* g_kv = (const float*)d_in[3];
  const float* b_kv = (const float*)d_in[4];
  const float* m_kv = (const float*)d_in[5];
  const float* v_kv = (const float*)d_in[6];
  const float* Wq   = (const float*)d_in[7];
  const float* bq   = (const float*)d_in[8];
  const float* g_q  = (const float*)d_in[9];
  const float* b_q  = (const float*)d_in[10];
  const float* m_q  = (const float*)d_in[11];
  const float* v_q  = (const float*)d_in[12];
  const float* Wp   = (const float*)d_in[13];
  const float* bp   = (const float*)d_in[14];
  const float* g_p  = (const float*)d_in[15];
  const float* b_p  = (const float*)d_in[16];
  const float* m_p  = (const float*)d_in[17];
  const float* v_p  = (const float*)d_in[18];

  char* ws = (char*)d_ws;
  bf16_t* xb   = (bf16_t*)ws; ws += (long)8 * 4096 * 256 * 2;
  bf16_t* WkT  = (bf16_t*)ws; ws += (long)128 * 256 * 2;
  bf16_t* WvT  = (bf16_t*)ws; ws += (long)512 * 256 * 2;
  bf16_t* Wq_t = (bf16_t*)ws; ws += (long)128 * 256 * 2;
  bf16_t* Wp_t = (bf16_t*)ws; ws += (long)512 * 512 * 2;
  bf16_t* Qbuf = (bf16_t*)ws; ws += (long)64 * 1024 * 16 * 2;
  bf16_t* Kbuf = (bf16_t*)ws; ws += (long)64 * 4096 * 16 * 2;
  bf16_t* Vtb  = (bf16_t*)ws; ws += (long)64 * 64 * 4096 * 2;
  bf16_t* outp = (bf16_t*)ws; ws += (long)8192 * 512 * 2;
  ws += 16384;  // slack

  cvt_f32_bf16<<<dim3(4096), 256, 0, stream>>>(x, xb, (long)8 * 4096 * 256);

  wkv_split_transpose<<<dim3(20, 8), dim3(32, 8), 0, stream>>>(Wkv, WkT, WvT);
  transpose_f32_bf16<<<dim3(4, 8),   dim3(32, 8), 0, stream>>>(Wq, Wq_t, 256, 128);
  transpose_f32_bf16<<<dim3(16, 16), dim3(32, 8), 0, stream>>>(Wp, Wp_t, 512, 512);

  gemm_bn<0><<<dim3(512, 2), 256, 0, stream>>>(xb, WkT, bkv, g_kv, b_kv, m_kv, v_kv, Kbuf, nullptr);
  gemm_bn<3><<<dim3(4096), 256, 0, stream>>>(WvT, xb, bkv, g_kv, b_kv, m_kv, v_kv, Vtb, nullptr);
  gemm_bn<1><<<dim3(128, 2), 256, 0, stream>>>(xb, Wq_t, bq, g_q, b_q, m_q, v_q, Qbuf, nullptr);

  attn_kernel<<<dim3(1024), 256, 0, stream>>>(Qbuf, Kbuf, Vtb, outp);

  gemm_bn<2><<<dim3(128, 8), 256, 0, stream>>>(outp, Wp_t, bp, g_p, b_p, m_p, v_p, nullptr, (float*)d_out);
}

// Round 6
// 239.199 us; speedup vs baseline: 1.3536x; 1.3536x over previous
//
#include <hip/hip_runtime.h>

typedef __bf16 bf16_t;
typedef __bf16 bf16x4 __attribute__((ext_vector_type(4)));
typedef __bf16 bf16x8 __attribute__((ext_vector_type(8)));
typedef short s16x4 __attribute__((ext_vector_type(4)));
typedef float f32x4 __attribute__((ext_vector_type(4)));

#define BN_EPS 1e-3f

#define GLOAD_LDS16(g, l) \
  __builtin_amdgcn_global_load_lds((const __attribute__((address_space(1))) void*)(g), \
                                   (__attribute__((address_space(3))) void*)(l), 16, 0, 0)

// ---------------- fp32 -> bf16 elementwise convert (8 elems/thread) ----------------
__global__ __launch_bounds__(256) void cvt_f32_bf16(
    const float* __restrict__ in, bf16_t* __restrict__ out, long n)
{
  long i = ((long)blockIdx.x * 256 + threadIdx.x) * 8;
  if (i + 8 > n) return;
  f32x4 a = *(const f32x4*)(in + i);
  f32x4 b = *(const f32x4*)(in + i + 4);
  bf16x8 o;
  o[0] = (bf16_t)a[0]; o[1] = (bf16_t)a[1]; o[2] = (bf16_t)a[2]; o[3] = (bf16_t)a[3];
  o[4] = (bf16_t)b[0]; o[5] = (bf16_t)b[1]; o[6] = (bf16_t)b[2]; o[7] = (bf16_t)b[3];
  *(bf16x8*)(out + i) = o;
}

// ---------------- weight transpose fp32 in[R][C] -> bf16 out[C][R] ----------------
__global__ __launch_bounds__(256) void transpose_f32_bf16(
    const float* __restrict__ in, bf16_t* __restrict__ out, int R, int C)
{
  __shared__ bf16_t t[32][33];
  int bx = blockIdx.x * 32, by = blockIdx.y * 32;
  int tx = threadIdx.x, ty = threadIdx.y;
#pragma unroll
  for (int i = 0; i < 32; i += 8)
    t[ty + i][tx] = (bf16_t)in[(long)(by + ty + i) * C + (bx + tx)];
  __syncthreads();
#pragma unroll
  for (int i = 0; i < 32; i += 8)
    out[(long)(bx + ty + i) * R + (by + tx)] = t[tx][ty + i];
}

// ------- Wkv split-transpose: fp32 [256][640] -> WkT[128][256], WvT[512][256] bf16 -------
__global__ __launch_bounds__(256) void wkv_split_transpose(
    const float* __restrict__ in, bf16_t* __restrict__ outK, bf16_t* __restrict__ outV)
{
  __shared__ bf16_t t[32][33];
  int bx = blockIdx.x * 32, by = blockIdx.y * 32;   // bx over 640 cols, by over 256 rows
  int tx = threadIdx.x, ty = threadIdx.y;
#pragma unroll
  for (int i = 0; i < 32; i += 8)
    t[ty + i][tx] = (bf16_t)in[(long)(by + ty + i) * 640 + (bx + tx)];
  __syncthreads();
#pragma unroll
  for (int i = 0; i < 32; i += 8) {
    int c = bx + ty + i;                 // kv channel 0..639
    int h = c / 80, r80 = c - h * 80;
    bf16_t v = t[tx][ty + i];
    if (r80 < 16)
      outK[(long)(h * 16 + r80) * 256 + (by + tx)] = v;
    else
      outV[(long)(h * 64 + (r80 - 16)) * 256 + (by + tx)] = v;
  }
}

// =============== fused QKV projection GEMM: x[32768,256] @ Wf[768,256]^T ===============
// R6. R4/R5 proved gemm<3> (and siblings) are vmem-REQUEST-throughput bound: time invariant
// (88.4 vs 88.0 us) under 7x FETCH drop + occupancy change; every wave streamed its full
// A/B panels from global (zero inter-wave reuse; compiler sank the R5 hoist -- VGPR 32).
// Fix = the guide's ladder step: LDS-staged 128x128 tile via global_load_lds, and FUSE
// K/V/Q projections (same A = xb; weights WkT|WvT|Wq_t are already contiguous in ws =
// one 768x256 matrix). xb read ONCE (16 MB, L3-hot) vs ~256 MB of panel re-reads.
//   - 512 thr / 8 waves (2x4), wave tile 64m x 32n, acc[4][2], K=256 single-shot.
//   - LDS 128 KB (Xs 64K + Ws 64K), 1 block/CU, grid 1536 = 256 mtiles x 6 ntiles,
//     bijective XCD decode: each XCD owns 32 contiguous mtiles (x-stripe 2MB fits L2).
//   - Swizzle (involution, both-sides): stored 16B-unit su = u ^ (row&7); staging keeps
//     the LDS dest LINEAR (gload_lds constraint) and pre-swizzles the SOURCE col; reads
//     XOR the same -> ds_read_b128 slot distribution balanced 8x8 (conflict-free).
//   - Epilogue per n-region (col<128: K-scatter; <640: V-interleave; else Q mask+scale),
//     formulas transplanted from the verified MODE 0/3/1 epilogues.
__global__ __launch_bounds__(512, 1) void qkv_fused(
    const bf16_t* __restrict__ xb, const bf16_t* __restrict__ Wf,
    const float* __restrict__ bkv, const float* __restrict__ g_kv,
    const float* __restrict__ b_kv, const float* __restrict__ m_kv,
    const float* __restrict__ v_kv,
    const float* __restrict__ bq, const float* __restrict__ g_q,
    const float* __restrict__ b_q, const float* __restrict__ m_q,
    const float* __restrict__ v_q,
    bf16_t* __restrict__ Kbuf, bf16_t* __restrict__ Vtb, bf16_t* __restrict__ Qbuf)
{
  __shared__ __align__(16) char Xs[65536];   // [128 rows][256 k] bf16, swizzled units
  __shared__ __align__(16) char Ws[65536];   // [128 rows][256 k] bf16, swizzled units

  const int tid = threadIdx.x;
  const int lane = tid & 63, w = tid >> 6;        // 8 waves
  const int quad = lane >> 4, l15 = lane & 15;
  const int wm = w >> 2, wn = w & 3;              // wave grid 2x4

  const int id = blockIdx.x;
  const int xcd = id & 7, slot = id >> 3;         // slot 0..191
  const int sd6 = slot / 6;
  const int mt = xcd * 32 + sd6;                  // 0..255 (contiguous per XCD)
  const int nt = slot - sd6 * 6;                  // 0..5
  const int blockM = mt * 128, blockN = nt * 128;

  // ---- stage both tiles: dest linear per wave, source col pre-swizzled ----
  {
    const int r_lo = w * 2 + (lane >> 5);                 // row within 16-row round
    const int soff = ((lane & 31) ^ (r_lo & 7)) << 4;     // swizzled source byte in row
#pragma unroll
    for (int rnd = 0; rnd < 8; rnd++) {
      const int row = rnd * 16 + r_lo;
      GLOAD_LDS16((const char*)xb + (long)(blockM + row) * 512 + soff,
                  &Xs[rnd * 8192 + w * 1024]);
      GLOAD_LDS16((const char*)Wf + (long)(blockN + row) * 512 + soff,
                  &Ws[rnd * 8192 + w * 1024]);
    }
  }
  __syncthreads();   // drains the 16 DMA loads (vmcnt0) + fences LDS

  // ---- MFMA: 8 k-steps x (4 mi x 2 ni) ----
  const int sw = l15 & 7;                 // row&7 for all frag rows (bases mult of 16)
  f32x4 acc[4][2] = {};
#pragma unroll
  for (int ks = 0; ks < 8; ks++) {
    const int u = ks * 4 + quad;          // logical 16B unit within row
    const int su = (u ^ sw) << 4;         // swizzled byte offset
    bf16x8 af[4];
#pragma unroll
    for (int mi = 0; mi < 4; mi++)
      af[mi] = *(const bf16x8*)(&Xs[(wm * 64 + mi * 16 + l15) * 512 + su]);
    bf16x8 bf_[2];
#pragma unroll
    for (int ni = 0; ni < 2; ni++)
      bf_[ni] = *(const bf16x8*)(&Ws[(wn * 32 + ni * 16 + l15) * 512 + su]);
#pragma unroll
    for (int mi = 0; mi < 4; mi++)
#pragma unroll
      for (int ni = 0; ni < 2; ni++)
        acc[mi][ni] = __builtin_amdgcn_mfma_f32_16x16x32_bf16(af[mi], bf_[ni], acc[mi][ni], 0, 0, 0);
  }

  // ---- epilogue: per n-region BN + scatter ----
#pragma unroll
  for (int ni = 0; ni < 2; ni++) {
    const int nfbase = blockN + wn * 32 + ni * 16;   // 16-col group, single region
    const int col = nfbase + l15;
    float s, t, bia;
    if (nfbase < 128) {            // K channels
      int cp = (col >> 4) * 80 + (col & 15);
      s = g_kv[cp] / sqrtf(v_kv[cp] + BN_EPS);
      t = b_kv[cp] - m_kv[cp] * s;
      bia = bkv[cp];
      int h = col >> 4, d = col & 15;
#pragma unroll
      for (int mi = 0; mi < 4; mi++)
#pragma unroll
        for (int r = 0; r < 4; r++) {
          int grow = blockM + wm * 64 + mi * 16 + quad * 4 + r;
          int b = grow >> 12, seq = grow & 4095;
          float y = (acc[mi][ni][r] + bia) * s + t;
          Kbuf[((long)((b * 8 + h) * 4096 + seq)) * 16 + d] = (bf16_t)y;
        }
    } else if (nfbase < 640) {     // V channels -> interleaved Vt
      int ch = col - 128;
      int cp = (ch >> 6) * 80 + 16 + (ch & 63);
      s = g_kv[cp] / sqrtf(v_kv[cp] + BN_EPS);
      t = b_kv[cp] - m_kv[cp] * s;
      bia = bkv[cp];
      int h2 = ch >> 6, dv = ch & 63;
#pragma unroll
      for (int mi = 0; mi < 4; mi++)
#pragma unroll
        for (int r = 0; r < 4; r++) {
          int grow = blockM + wm * 64 + mi * 16 + quad * 4 + r;
          int b = grow >> 12, seq = grow & 4095;
          int kb = seq >> 5, s32 = seq & 31;
          int qd = (s32 & 15) >> 2, j = (s32 >> 4) * 4 + (s32 & 3);
          float y = (acc[mi][ni][r] + bia) * s + t;
          Vtb[(((long)(b * 8 + h2)) << 18) + (kb << 11) + (qd << 9) + (dv << 3) + j] = (bf16_t)y;
        }
    } else {                        // Q channels (write only strided-subsampled rows)
      int qc = col - 640;
      s = g_q[qc] / sqrtf(v_q[qc] + BN_EPS);
      t = b_q[qc] - m_q[qc] * s;
      bia = bq[qc];
      int h = qc >> 4, d = qc & 15;
#pragma unroll
      for (int mi = 0; mi < 4; mi++) {
        // row parity bit6 is uniform per mi (blockM, wm*64, mi*16 only); bit0 = r
        if ((((blockM + wm * 64 + mi * 16) >> 6) & 1) != 0) continue;
#pragma unroll
        for (int r = 0; r < 4; r += 2) {
          int grow = blockM + wm * 64 + mi * 16 + quad * 4 + r;
          int b = grow >> 12, seq = grow & 4095;
          int qp = ((seq >> 7) << 5) + ((seq & 63) >> 1);
          float y = (acc[mi][ni][r] + bia) * s + t;
          Qbuf[((long)((b * 8 + h) * 1024 + qp)) * 16 + d] = (bf16_t)(y * 0.36067376f);
        }
      }
    }
  }
}

// ---------------- gemm_bn: retained for MODE 2 (PROJ) only ----------------
// MODE 2: PROJ A=outp[8192][512], WpT[512][512] -> d_out fp32 [8192][512]
template <int MODE>
__global__ __launch_bounds__(256, 2) void gemm_bn(
    const bf16_t* __restrict__ A, const bf16_t* __restrict__ Wt,
    const float* __restrict__ bias, const float* __restrict__ gamma,
    const float* __restrict__ beta, const float* __restrict__ mean,
    const float* __restrict__ var,
    bf16_t* __restrict__ out0, float* __restrict__ outf)
{
  constexpr int KTOT = (MODE == 2) ? 512 : 256;
  const int lane = threadIdx.x & 63;
  const int w = threadIdx.x >> 6;
  const int quad = lane >> 4, l15 = lane & 15;
  const int m0 = blockIdx.x * 64 + w * 16;
  const int n0 = blockIdx.y * 64;

  int mrow = m0 + l15;
  const bf16_t* ap = A + (long)mrow * KTOT + quad * 8;
  const bf16_t* bp = Wt + (long)(n0 + l15) * KTOT + quad * 8;

  f32x4 acc[4] = {};
#pragma unroll
  for (int kc = 0; kc < KTOT / 256; kc++) {
    bf16x8 a[8];
    bf16x8 bfr[4][8];
#pragma unroll
    for (int ks = 0; ks < 8; ks++)
      a[ks] = *(const bf16x8*)(ap + kc * 256 + ks * 32);
#pragma unroll
    for (int nt = 0; nt < 4; nt++)
#pragma unroll
      for (int ks = 0; ks < 8; ks++)
        bfr[nt][ks] = *(const bf16x8*)(bp + (long)nt * 16 * KTOT + kc * 256 + ks * 32);
#pragma unroll
    for (int ks = 0; ks < 8; ks++)
#pragma unroll
      for (int nt = 0; nt < 4; nt++)
        acc[nt] = __builtin_amdgcn_mfma_f32_16x16x32_bf16(a[ks], bfr[nt][ks], acc[nt], 0, 0, 0);
  }

#pragma unroll
  for (int nt = 0; nt < 4; nt++) {
    int col = n0 + nt * 16 + l15;
    float s = gamma[col] / sqrtf(var[col] + BN_EPS);
    float t = beta[col] - mean[col] * s;
    float bia = bias[col];
#pragma unroll
    for (int r = 0; r < 4; r++) {
      int grow = m0 + quad * 4 + r;
      float y = (acc[nt][r] + bia) * s + t;
      outf[(long)grow * 512 + col] = y;
    }
  }
}

// ---------------- flash attention: all-x32 MFMA, 4-wave blocks, depth-2 counted vmcnt ----------------
// (unchanged from R4/R5; ~76 us, next round's target)
__global__ __launch_bounds__(256, 4) void attn_kernel(
    const bf16_t* __restrict__ Q, const bf16_t* __restrict__ K,
    const bf16_t* __restrict__ Vt, bf16_t* __restrict__ outp)
{
  const int tid = threadIdx.x;
  const int lane = tid & 63, w = tid >> 6;                // 4 waves
  const int quad = lane >> 4, l15 = lane & 15;
  const int bh = blockIdx.x & 63, qb = blockIdx.x >> 6;   // qb 0..15
  const int b = bh >> 3, h = bh & 7;
  const bf16_t* Qp = Q + (long)bh * 1024 * 16;
  const char* Kg = (const char*)(K + (long)bh * 4096 * 16);     // [key][16d], 32 B/row
  const char* Vg = (const char*)(Vt + ((long)bh << 18));        // interleaved, 512 KB/bh

  __shared__ __align__(16) char Kl[4][2048];
  __shared__ __align__(16) char Vl[4][8192];

  const int q0 = qb * 64 + w * 16;
  bf16x8 qB8;
  {
    bf16x8 qv = *(const bf16x8*)(Qp + (long)(q0 + l15) * 16 + (quad & 1) * 8);
    bf16x8 zq = {};
    qB8 = (quad < 2) ? qv : zq;
  }

  f32x4 O[4] = {};
  f32x4 lpacc = {};
  const f32x4 zf = {0.f, 0.f, 0.f, 0.f};

  bf16x8 ones8;
#pragma unroll
  for (int i = 0; i < 8; i++) ones8[i] = (bf16_t)1.f;

  const char* vsrc = Vg + (long)lane * 16;
  const char* ksrc = Kg + (long)lane * 32 + (w - 2) * 16;

  auto stage = [&](int t, int buf) {
    if (w < 2) {
#pragma unroll
      for (int c = 0; c < 2; c++)
        GLOAD_LDS16(vsrc + (long)t * 8192 + (w * 2 + c) * 1024, &Vl[buf][(w * 2 + c) * 1024]);
    } else {
#pragma unroll
      for (int c = 0; c < 2; c++)
        GLOAD_LDS16(vsrc + (long)t * 8192 + ((w - 2) * 2 + 4 + c) * 1024,
                    &Vl[buf][((w - 2) * 2 + 4 + c) * 1024]);
      GLOAD_LDS16(ksrc + (long)t * 2048, &Kl[buf][(w - 2) * 1024]);
    }
  };

  const int krow_off = (quad & 1) * 1024;

  auto compute = [&](int buf) {
#pragma unroll
    for (int kh = 0; kh < 2; kh++) {
      bf16x8 k0 = *(const bf16x8*)(&Kl[buf][krow_off + (kh * 32 + l15) * 16]);
      bf16x8 k1 = *(const bf16x8*)(&Kl[buf][krow_off + (kh * 32 + 16 + l15) * 16]);
      f32x4 S0 = __builtin_amdgcn_mfma_f32_16x16x32_bf16(k0, qB8, zf, 0, 0, 0);
      f32x4 S1 = __builtin_amdgcn_mfma_f32_16x16x32_bf16(k1, qB8, zf, 0, 0, 0);
      bf16x8 pb;
      pb[0] = (bf16_t)__builtin_amdgcn_exp2f(S0[0]);
      pb[1] = (bf16_t)__builtin_amdgcn_exp2f(S0[1]);
      pb[2] = (bf16_t)__builtin_amdgcn_exp2f(S0[2]);
      pb[3] = (bf16_t)__builtin_amdgcn_exp2f(S0[3]);
      pb[4] = (bf16_t)__builtin_amdgcn_exp2f(S1[0]);
      pb[5] = (bf16_t)__builtin_amdgcn_exp2f(S1[1]);
      pb[6] = (bf16_t)__builtin_amdgcn_exp2f(S1[2]);
      pb[7] = (bf16_t)__builtin_amdgcn_exp2f(S1[3]);
      lpacc = __builtin_amdgcn_mfma_f32_16x16x32_bf16(ones8, pb, lpacc, 0, 0, 0);
#pragma unroll
      for (int dt = 0; dt < 4; dt++) {
        bf16x8 vA = *(const bf16x8*)(&Vl[buf][kh * 4096 + quad * 1024 + (dt * 16 + l15) * 16]);
        O[dt] = __builtin_amdgcn_mfma_f32_16x16x32_bf16(vA, pb, O[dt], 0, 0, 0);
      }
    }
  };

  stage(0, 0);
  stage(1, 1);
#pragma unroll 4
  for (int t = 0; t < 64; t++) {
    if (t < 63) {
      if (w < 2) asm volatile("s_waitcnt vmcnt(2)" ::: "memory");
      else       asm volatile("s_waitcnt vmcnt(3)" ::: "memory");
    } else {
      asm volatile("s_waitcnt vmcnt(0)" ::: "memory");
    }
    __builtin_amdgcn_s_barrier();
    __builtin_amdgcn_sched_barrier(0);
    if (t + 2 < 64) stage(t + 2, (t + 2) & 3);
    compute(t & 3);
  }

  float rl = __builtin_amdgcn_rcpf(lpacc[0]);
  int q = q0 + l15;
  long colq = q & 511;
  long rowbase = (long)b * 1024 + (long)h * 128 + (q >> 9);
#pragma unroll
  for (int dt = 0; dt < 4; dt++) {
#pragma unroll
    for (int r = 0; r < 4; r++) {
      int dv = dt * 16 + quad * 4 + r;
      float val = O[dt][r] * rl;
      float hs = val * fminf(fmaxf(val + 3.f, 0.f), 6.f) * (1.f / 6.f);
      outp[(rowbase + (long)dv * 2) * 512 + colq] = (bf16_t)hs;
    }
  }
}

extern "C" void kernel_launch(void* const* d_in, const int* in_sizes, int n_in,
                              void* d_out, int out_size, void* d_ws, size_t ws_size,
                              hipStream_t stream)
{
  const float* x    = (const float*)d_in[0];
  const float* Wkv  = (const float*)d_in[1];
  const float* bkv  = (const float*)d_in[2];
  const float* g_kv = (const float*)d_in[3];
  const float* b_kv = (const float*)d_in[4];
  const float* m_kv = (const float*)d_in[5];
  const float* v_kv = (const float*)d_in[6];
  const float* Wq   = (const float*)d_in[7];
  const float* bq   = (const float*)d_in[8];
  const float* g_q  = (const float*)d_in[9];
  const float* b_q  = (const float*)d_in[10];
  const float* m_q  = (const float*)d_in[11];
  const float* v_q  = (const float*)d_in[12];
  const float* Wp   = (const float*)d_in[13];
  const float* bp   = (const float*)d_in[14];
  const float* g_p  = (const float*)d_in[15];
  const float* b_p  = (const float*)d_in[16];
  const float* m_p  = (const float*)d_in[17];
  const float* v_p  = (const float*)d_in[18];

  char* ws = (char*)d_ws;
  bf16_t* xb   = (bf16_t*)ws; ws += (long)8 * 4096 * 256 * 2;
  bf16_t* WkT  = (bf16_t*)ws; ws += (long)128 * 256 * 2;   // | contiguous: Wf[768][256]
  bf16_t* WvT  = (bf16_t*)ws; ws += (long)512 * 256 * 2;   // |
  bf16_t* Wq_t = (bf16_t*)ws; ws += (long)128 * 256 * 2;   // |
  bf16_t* Wp_t = (bf16_t*)ws; ws += (long)512 * 512 * 2;
  bf16_t* Qbuf = (bf16_t*)ws; ws += (long)64 * 1024 * 16 * 2;
  bf16_t* Kbuf = (bf16_t*)ws; ws += (long)64 * 4096 * 16 * 2;
  bf16_t* Vtb  = (bf16_t*)ws; ws += (long)64 * 64 * 4096 * 2;
  bf16_t* outp = (bf16_t*)ws; ws += (long)8192 * 512 * 2;
  ws += 16384;  // slack

  cvt_f32_bf16<<<dim3(4096), 256, 0, stream>>>(x, xb, (long)8 * 4096 * 256);

  wkv_split_transpose<<<dim3(20, 8), dim3(32, 8), 0, stream>>>(Wkv, WkT, WvT);
  transpose_f32_bf16<<<dim3(4, 8),   dim3(32, 8), 0, stream>>>(Wq, Wq_t, 256, 128);
  transpose_f32_bf16<<<dim3(16, 16), dim3(32, 8), 0, stream>>>(Wp, Wp_t, 512, 512);

  // fused K/V/Q projection (replaces gemm<0>, gemm<3>, gemm<1>)
  qkv_fused<<<dim3(1536), 512, 0, stream>>>(xb, WkT,
      bkv, g_kv, b_kv, m_kv, v_kv, bq, g_q, b_q, m_q, v_q,
      Kbuf, Vtb, Qbuf);

  attn_kernel<<<dim3(1024), 256, 0, stream>>>(Qbuf, Kbuf, Vtb, outp);

  gemm_bn<2><<<dim3(128, 8), 256, 0, stream>>>(outp, Wp_t, bp, g_p, b_p, m_p, v_p, nullptr, (float*)d_out);
}

// Round 7
// 213.692 us; speedup vs baseline: 1.5151x; 1.1194x over previous
//
#include <hip/hip_runtime.h>

typedef __bf16 bf16_t;
typedef __bf16 bf16x4 __attribute__((ext_vector_type(4)));
typedef __bf16 bf16x8 __attribute__((ext_vector_type(8)));
typedef short s16x4 __attribute__((ext_vector_type(4)));
typedef float f32x4 __attribute__((ext_vector_type(4)));

#define BN_EPS 1e-3f

#define GLOAD_LDS16(g, l) \
  __builtin_amdgcn_global_load_lds((const __attribute__((address_space(1))) void*)(g), \
                                   (__attribute__((address_space(3))) void*)(l), 16, 0, 0)

// ---------------- fp32 -> bf16 elementwise convert (8 elems/thread) ----------------
__global__ __launch_bounds__(256) void cvt_f32_bf16(
    const float* __restrict__ in, bf16_t* __restrict__ out, long n)
{
  long i = ((long)blockIdx.x * 256 + threadIdx.x) * 8;
  if (i + 8 > n) return;
  f32x4 a = *(const f32x4*)(in + i);
  f32x4 b = *(const f32x4*)(in + i + 4);
  bf16x8 o;
  o[0] = (bf16_t)a[0]; o[1] = (bf16_t)a[1]; o[2] = (bf16_t)a[2]; o[3] = (bf16_t)a[3];
  o[4] = (bf16_t)b[0]; o[5] = (bf16_t)b[1]; o[6] = (bf16_t)b[2]; o[7] = (bf16_t)b[3];
  *(bf16x8*)(out + i) = o;
}

// ---------------- weight transpose fp32 in[R][C] -> bf16 out[C][R] ----------------
__global__ __launch_bounds__(256) void transpose_f32_bf16(
    const float* __restrict__ in, bf16_t* __restrict__ out, int R, int C)
{
  __shared__ bf16_t t[32][33];
  int bx = blockIdx.x * 32, by = blockIdx.y * 32;
  int tx = threadIdx.x, ty = threadIdx.y;
#pragma unroll
  for (int i = 0; i < 32; i += 8)
    t[ty + i][tx] = (bf16_t)in[(long)(by + ty + i) * C + (bx + tx)];
  __syncthreads();
#pragma unroll
  for (int i = 0; i < 32; i += 8)
    out[(long)(bx + ty + i) * R + (by + tx)] = t[tx][ty + i];
}

// ------- Wkv split-transpose: fp32 [256][640] -> WkT[128][256], WvT[512][256] bf16 -------
__global__ __launch_bounds__(256) void wkv_split_transpose(
    const float* __restrict__ in, bf16_t* __restrict__ outK, bf16_t* __restrict__ outV)
{
  __shared__ bf16_t t[32][33];
  int bx = blockIdx.x * 32, by = blockIdx.y * 32;   // bx over 640 cols, by over 256 rows
  int tx = threadIdx.x, ty = threadIdx.y;
#pragma unroll
  for (int i = 0; i < 32; i += 8)
    t[ty + i][tx] = (bf16_t)in[(long)(by + ty + i) * 640 + (bx + tx)];
  __syncthreads();
#pragma unroll
  for (int i = 0; i < 32; i += 8) {
    int c = bx + ty + i;                 // kv channel 0..639
    int h = c / 80, r80 = c - h * 80;
    bf16_t v = t[tx][ty + i];
    if (r80 < 16)
      outK[(long)(h * 16 + r80) * 256 + (by + tx)] = v;
    else
      outV[(long)(h * 64 + (r80 - 16)) * 256 + (by + tx)] = v;
  }
}

// =============== fused QKV projection GEMM: x[32768,256] @ Wf[768,256]^T ===============
// (R6, unchanged; proven: replaced ~150 us of register-streamed GEMMs, <66 us)
__global__ __launch_bounds__(512, 1) void qkv_fused(
    const bf16_t* __restrict__ xb, const bf16_t* __restrict__ Wf,
    const float* __restrict__ bkv, const float* __restrict__ g_kv,
    const float* __restrict__ b_kv, const float* __restrict__ m_kv,
    const float* __restrict__ v_kv,
    const float* __restrict__ bq, const float* __restrict__ g_q,
    const float* __restrict__ b_q, const float* __restrict__ m_q,
    const float* __restrict__ v_q,
    bf16_t* __restrict__ Kbuf, bf16_t* __restrict__ Vtb, bf16_t* __restrict__ Qbuf)
{
  __shared__ __align__(16) char Xs[65536];   // [128 rows][256 k] bf16, swizzled units
  __shared__ __align__(16) char Ws[65536];   // [128 rows][256 k] bf16, swizzled units

  const int tid = threadIdx.x;
  const int lane = tid & 63, w = tid >> 6;        // 8 waves
  const int quad = lane >> 4, l15 = lane & 15;
  const int wm = w >> 2, wn = w & 3;              // wave grid 2x4

  const int id = blockIdx.x;
  const int xcd = id & 7, slot = id >> 3;         // slot 0..191
  const int sd6 = slot / 6;
  const int mt = xcd * 32 + sd6;                  // 0..255 (contiguous per XCD)
  const int nt = slot - sd6 * 6;                  // 0..5
  const int blockM = mt * 128, blockN = nt * 128;

  // ---- stage both tiles: dest linear per wave, source col pre-swizzled ----
  {
    const int r_lo = w * 2 + (lane >> 5);                 // row within 16-row round
    const int soff = ((lane & 31) ^ (r_lo & 7)) << 4;     // swizzled source byte in row
#pragma unroll
    for (int rnd = 0; rnd < 8; rnd++) {
      const int row = rnd * 16 + r_lo;
      GLOAD_LDS16((const char*)xb + (long)(blockM + row) * 512 + soff,
                  &Xs[rnd * 8192 + w * 1024]);
      GLOAD_LDS16((const char*)Wf + (long)(blockN + row) * 512 + soff,
                  &Ws[rnd * 8192 + w * 1024]);
    }
  }
  __syncthreads();   // drains the 16 DMA loads (vmcnt0) + fences LDS

  // ---- MFMA: 8 k-steps x (4 mi x 2 ni) ----
  const int sw = l15 & 7;                 // row&7 for all frag rows (bases mult of 16)
  f32x4 acc[4][2] = {};
#pragma unroll
  for (int ks = 0; ks < 8; ks++) {
    const int u = ks * 4 + quad;          // logical 16B unit within row
    const int su = (u ^ sw) << 4;         // swizzled byte offset
    bf16x8 af[4];
#pragma unroll
    for (int mi = 0; mi < 4; mi++)
      af[mi] = *(const bf16x8*)(&Xs[(wm * 64 + mi * 16 + l15) * 512 + su]);
    bf16x8 bf_[2];
#pragma unroll
    for (int ni = 0; ni < 2; ni++)
      bf_[ni] = *(const bf16x8*)(&Ws[(wn * 32 + ni * 16 + l15) * 512 + su]);
#pragma unroll
    for (int mi = 0; mi < 4; mi++)
#pragma unroll
      for (int ni = 0; ni < 2; ni++)
        acc[mi][ni] = __builtin_amdgcn_mfma_f32_16x16x32_bf16(af[mi], bf_[ni], acc[mi][ni], 0, 0, 0);
  }

  // ---- epilogue: per n-region BN + scatter ----
#pragma unroll
  for (int ni = 0; ni < 2; ni++) {
    const int nfbase = blockN + wn * 32 + ni * 16;   // 16-col group, single region
    const int col = nfbase + l15;
    float s, t, bia;
    if (nfbase < 128) {            // K channels
      int cp = (col >> 4) * 80 + (col & 15);
      s = g_kv[cp] / sqrtf(v_kv[cp] + BN_EPS);
      t = b_kv[cp] - m_kv[cp] * s;
      bia = bkv[cp];
      int h = col >> 4, d = col & 15;
#pragma unroll
      for (int mi = 0; mi < 4; mi++)
#pragma unroll
        for (int r = 0; r < 4; r++) {
          int grow = blockM + wm * 64 + mi * 16 + quad * 4 + r;
          int b = grow >> 12, seq = grow & 4095;
          float y = (acc[mi][ni][r] + bia) * s + t;
          Kbuf[((long)((b * 8 + h) * 4096 + seq)) * 16 + d] = (bf16_t)y;
        }
    } else if (nfbase < 640) {     // V channels -> interleaved Vt
      int ch = col - 128;
      int cp = (ch >> 6) * 80 + 16 + (ch & 63);
      s = g_kv[cp] / sqrtf(v_kv[cp] + BN_EPS);
      t = b_kv[cp] - m_kv[cp] * s;
      bia = bkv[cp];
      int h2 = ch >> 6, dv = ch & 63;
#pragma unroll
      for (int mi = 0; mi < 4; mi++)
#pragma unroll
        for (int r = 0; r < 4; r++) {
          int grow = blockM + wm * 64 + mi * 16 + quad * 4 + r;
          int b = grow >> 12, seq = grow & 4095;
          int kb = seq >> 5, s32 = seq & 31;
          int qd = (s32 & 15) >> 2, j = (s32 >> 4) * 4 + (s32 & 3);
          float y = (acc[mi][ni][r] + bia) * s + t;
          Vtb[(((long)(b * 8 + h2)) << 18) + (kb << 11) + (qd << 9) + (dv << 3) + j] = (bf16_t)y;
        }
    } else {                        // Q channels (write only strided-subsampled rows)
      int qc = col - 640;
      s = g_q[qc] / sqrtf(v_q[qc] + BN_EPS);
      t = b_q[qc] - m_q[qc] * s;
      bia = bq[qc];
      int h = qc >> 4, d = qc & 15;
#pragma unroll
      for (int mi = 0; mi < 4; mi++) {
        // row parity bit6 is uniform per mi (blockM, wm*64, mi*16 only); bit0 = r
        if ((((blockM + wm * 64 + mi * 16) >> 6) & 1) != 0) continue;
#pragma unroll
        for (int r = 0; r < 4; r += 2) {
          int grow = blockM + wm * 64 + mi * 16 + quad * 4 + r;
          int b = grow >> 12, seq = grow & 4095;
          int qp = ((seq >> 7) << 5) + ((seq & 63) >> 1);
          float y = (acc[mi][ni][r] + bia) * s + t;
          Qbuf[((long)((b * 8 + h) * 1024 + qp)) * 16 + d] = (bf16_t)(y * 0.36067376f);
        }
      }
    }
  }
}

// =============== fused output projection: outp[8192,512] @ WpT[512,512]^T + BN ===============
// R7. gemm<2> was the last register-streamed GEMM (same vmem-request disease R4/R5 proved:
// ~80 naked panel loads/wave-tile, zero inter-wave reuse; scaled estimate ~45 us). Same cure
// as qkv_fused: LDS-staged 128x128 tile, K=512 in TWO 256-chunks (Xs/Ws 64KB each = 128 KB,
// 1 block/CU), source+read XOR-swizzle involution, XCD-contiguous m-stripes.
// Grid 256 = 64 mt x 4 nt: xcd=id&7 owns mt = xcd*8..+7 (1 MB A-stripe fits XCD L2).
// Floor: 16 MB fp32 write + ~9 MB read + 4.3 GFLOP ~= 10-14 us.
__global__ __launch_bounds__(512, 1) void proj_fused(
    const bf16_t* __restrict__ A, const bf16_t* __restrict__ Wt,
    const float* __restrict__ bias, const float* __restrict__ gamma,
    const float* __restrict__ beta, const float* __restrict__ mean,
    const float* __restrict__ var, float* __restrict__ outf)
{
  __shared__ __align__(16) char Xs[65536];   // [128 rows][256 k-chunk] bf16
  __shared__ __align__(16) char Wl[65536];

  const int tid = threadIdx.x;
  const int lane = tid & 63, w = tid >> 6;        // 8 waves
  const int quad = lane >> 4, l15 = lane & 15;
  const int wm = w >> 2, wn = w & 3;              // wave grid 2x4

  const int id = blockIdx.x;                      // 0..255
  const int xcd = id & 7, slot = id >> 3;         // slot 0..31
  const int mt = xcd * 8 + (slot >> 2);           // 0..63 (contiguous per XCD)
  const int nt = slot & 3;                        // 0..3
  const int blockM = mt * 128, blockN = nt * 128;

  const int r_lo = w * 2 + (lane >> 5);                 // 0..15
  const int soff = ((lane & 31) ^ (r_lo & 7)) << 4;     // swizzled source byte in chunk-row
  const int sw = l15 & 7;
  f32x4 acc[4][2] = {};

#pragma unroll
  for (int kc = 0; kc < 2; kc++) {
    if (kc) __syncthreads();                      // all reads of chunk 0 done before overwrite
#pragma unroll
    for (int rnd = 0; rnd < 8; rnd++) {
      const int row = rnd * 16 + r_lo;
      GLOAD_LDS16((const char*)A  + (long)(blockM + row) * 1024 + kc * 512 + soff,
                  &Xs[rnd * 8192 + w * 1024]);
      GLOAD_LDS16((const char*)Wt + (long)(blockN + row) * 1024 + kc * 512 + soff,
                  &Wl[rnd * 8192 + w * 1024]);
    }
    __syncthreads();                              // drains DMA (vmcnt0) + fences LDS

#pragma unroll
    for (int ks = 0; ks < 8; ks++) {
      const int u = ks * 4 + quad;                // 16B unit within 512B chunk-row
      const int su = (u ^ sw) << 4;
      bf16x8 af[4];
#pragma unroll
      for (int mi = 0; mi < 4; mi++)
        af[mi] = *(const bf16x8*)(&Xs[(wm * 64 + mi * 16 + l15) * 512 + su]);
      bf16x8 bw[2];
#pragma unroll
      for (int ni = 0; ni < 2; ni++)
        bw[ni] = *(const bf16x8*)(&Wl[(wn * 32 + ni * 16 + l15) * 512 + su]);
#pragma unroll
      for (int mi = 0; mi < 4; mi++)
#pragma unroll
        for (int ni = 0; ni < 2; ni++)
          acc[mi][ni] = __builtin_amdgcn_mfma_f32_16x16x32_bf16(af[mi], bw[ni], acc[mi][ni], 0, 0, 0);
    }
  }

  // ---- epilogue: BN + fp32 store (transplanted from verified MODE 2) ----
#pragma unroll
  for (int ni = 0; ni < 2; ni++) {
    int col = blockN + wn * 32 + ni * 16 + l15;
    float s = gamma[col] / sqrtf(var[col] + BN_EPS);
    float t = beta[col] - mean[col] * s;
    float bia = bias[col];
#pragma unroll
    for (int mi = 0; mi < 4; mi++)
#pragma unroll
      for (int r = 0; r < 4; r++) {
        int grow = blockM + wm * 64 + mi * 16 + quad * 4 + r;
        float y = (acc[mi][ni][r] + bia) * s + t;
        outf[(long)grow * 512 + col] = y;
      }
  }
}

// ---------------- flash attention: all-x32 MFMA, 4-wave blocks, depth-3 counted vmcnt ----------------
// R7 delta: prefetch depth 2 -> 3 (prologue stages 3 tiles; wait allows TWO future tiles in
// flight: vmcnt(4|6); stage(t+3) after the barrier lands in buf (t-1)&3, which every wave
// finished computing before arriving at barrier t -- race-free, same 4 buffers / 40 KB).
// R4/R6 accounting: MFMA-busy 25 us + VALU-busy 29 us (exp2 ~14 us irreducible), ~12 us
// stall = barrier-arrival skew on the depth-1-in-flight wait. Deeper pipeline absorbs it.
__global__ __launch_bounds__(256, 4) void attn_kernel(
    const bf16_t* __restrict__ Q, const bf16_t* __restrict__ K,
    const bf16_t* __restrict__ Vt, bf16_t* __restrict__ outp)
{
  const int tid = threadIdx.x;
  const int lane = tid & 63, w = tid >> 6;                // 4 waves
  const int quad = lane >> 4, l15 = lane & 15;
  const int bh = blockIdx.x & 63, qb = blockIdx.x >> 6;   // qb 0..15
  const int b = bh >> 3, h = bh & 7;
  const bf16_t* Qp = Q + (long)bh * 1024 * 16;
  const char* Kg = (const char*)(K + (long)bh * 4096 * 16);     // [key][16d], 32 B/row
  const char* Vg = (const char*)(Vt + ((long)bh << 18));        // interleaved, 512 KB/bh

  __shared__ __align__(16) char Kl[4][2048];
  __shared__ __align__(16) char Vl[4][8192];

  const int q0 = qb * 64 + w * 16;
  bf16x8 qB8;
  {
    bf16x8 qv = *(const bf16x8*)(Qp + (long)(q0 + l15) * 16 + (quad & 1) * 8);
    bf16x8 zq = {};
    qB8 = (quad < 2) ? qv : zq;
  }

  f32x4 O[4] = {};
  f32x4 lpacc = {};
  const f32x4 zf = {0.f, 0.f, 0.f, 0.f};

  bf16x8 ones8;
#pragma unroll
  for (int i = 0; i < 8; i++) ones8[i] = (bf16_t)1.f;

  const char* vsrc = Vg + (long)lane * 16;
  const char* ksrc = Kg + (long)lane * 32 + (w - 2) * 16;

  auto stage = [&](int t, int buf) {
    if (w < 2) {
#pragma unroll
      for (int c = 0; c < 2; c++)
        GLOAD_LDS16(vsrc + (long)t * 8192 + (w * 2 + c) * 1024, &Vl[buf][(w * 2 + c) * 1024]);
    } else {
#pragma unroll
      for (int c = 0; c < 2; c++)
        GLOAD_LDS16(vsrc + (long)t * 8192 + ((w - 2) * 2 + 4 + c) * 1024,
                    &Vl[buf][((w - 2) * 2 + 4 + c) * 1024]);
      GLOAD_LDS16(ksrc + (long)t * 2048, &Kl[buf][(w - 2) * 1024]);
    }
  };

  const int krow_off = (quad & 1) * 1024;

  auto compute = [&](int buf) {
#pragma unroll
    for (int kh = 0; kh < 2; kh++) {
      bf16x8 k0 = *(const bf16x8*)(&Kl[buf][krow_off + (kh * 32 + l15) * 16]);
      bf16x8 k1 = *(const bf16x8*)(&Kl[buf][krow_off + (kh * 32 + 16 + l15) * 16]);
      f32x4 S0 = __builtin_amdgcn_mfma_f32_16x16x32_bf16(k0, qB8, zf, 0, 0, 0);
      f32x4 S1 = __builtin_amdgcn_mfma_f32_16x16x32_bf16(k1, qB8, zf, 0, 0, 0);
      bf16x8 pb;
      pb[0] = (bf16_t)__builtin_amdgcn_exp2f(S0[0]);
      pb[1] = (bf16_t)__builtin_amdgcn_exp2f(S0[1]);
      pb[2] = (bf16_t)__builtin_amdgcn_exp2f(S0[2]);
      pb[3] = (bf16_t)__builtin_amdgcn_exp2f(S0[3]);
      pb[4] = (bf16_t)__builtin_amdgcn_exp2f(S1[0]);
      pb[5] = (bf16_t)__builtin_amdgcn_exp2f(S1[1]);
      pb[6] = (bf16_t)__builtin_amdgcn_exp2f(S1[2]);
      pb[7] = (bf16_t)__builtin_amdgcn_exp2f(S1[3]);
      lpacc = __builtin_amdgcn_mfma_f32_16x16x32_bf16(ones8, pb, lpacc, 0, 0, 0);
#pragma unroll
      for (int dt = 0; dt < 4; dt++) {
        bf16x8 vA = *(const bf16x8*)(&Vl[buf][kh * 4096 + quad * 1024 + (dt * 16 + l15) * 16]);
        O[dt] = __builtin_amdgcn_mfma_f32_16x16x32_bf16(vA, pb, O[dt], 0, 0, 0);
      }
    }
  };

  stage(0, 0);
  stage(1, 1);
  stage(2, 2);
#pragma unroll 4
  for (int t = 0; t < 64; t++) {
    if (t + 2 < 64) {              // tiles t+1, t+2 may stay in flight
      if (w < 2) asm volatile("s_waitcnt vmcnt(4)" ::: "memory");
      else       asm volatile("s_waitcnt vmcnt(6)" ::: "memory");
    } else if (t + 1 < 64) {       // only t+1 outstanding
      if (w < 2) asm volatile("s_waitcnt vmcnt(2)" ::: "memory");
      else       asm volatile("s_waitcnt vmcnt(3)" ::: "memory");
    } else {
      asm volatile("s_waitcnt vmcnt(0)" ::: "memory");
    }
    __builtin_amdgcn_s_barrier();
    __builtin_amdgcn_sched_barrier(0);
    if (t + 3 < 64) stage(t + 3, (t + 3) & 3);   // buf (t-1)&3: freed by all waves pre-barrier
    compute(t & 3);
  }

  float rl = __builtin_amdgcn_rcpf(lpacc[0]);
  int q = q0 + l15;
  long colq = q & 511;
  long rowbase = (long)b * 1024 + (long)h * 128 + (q >> 9);
#pragma unroll
  for (int dt = 0; dt < 4; dt++) {
#pragma unroll
    for (int r = 0; r < 4; r++) {
      int dv = dt * 16 + quad * 4 + r;
      float val = O[dt][r] * rl;
      float hs = val * fminf(fmaxf(val + 3.f, 0.f), 6.f) * (1.f / 6.f);
      outp[(rowbase + (long)dv * 2) * 512 + colq] = (bf16_t)hs;
    }
  }
}

extern "C" void kernel_launch(void* const* d_in, const int* in_sizes, int n_in,
                              void* d_out, int out_size, void* d_ws, size_t ws_size,
                              hipStream_t stream)
{
  const float* x    = (const float*)d_in[0];
  const float* Wkv  = (const float*)d_in[1];
  const float* bkv  = (const float*)d_in[2];
  const float* g_kv = (const float*)d_in[3];
  const float* b_kv = (const float*)d_in[4];
  const float* m_kv = (const float*)d_in[5];
  const float* v_kv = (const float*)d_in[6];
  const float* Wq   = (const float*)d_in[7];
  const float* bq   = (const float*)d_in[8];
  const float* g_q  = (const float*)d_in[9];
  const float* b_q  = (const float*)d_in[10];
  const float* m_q  = (const float*)d_in[11];
  const float* v_q  = (const float*)d_in[12];
  const float* Wp   = (const float*)d_in[13];
  const float* bp   = (const float*)d_in[14];
  const float* g_p  = (const float*)d_in[15];
  const float* b_p  = (const float*)d_in[16];
  const float* m_p  = (const float*)d_in[17];
  const float* v_p  = (const float*)d_in[18];

  char* ws = (char*)d_ws;
  bf16_t* xb   = (bf16_t*)ws; ws += (long)8 * 4096 * 256 * 2;
  bf16_t* WkT  = (bf16_t*)ws; ws += (long)128 * 256 * 2;   // | contiguous: Wf[768][256]
  bf16_t* WvT  = (bf16_t*)ws; ws += (long)512 * 256 * 2;   // |
  bf16_t* Wq_t = (bf16_t*)ws; ws += (long)128 * 256 * 2;   // |
  bf16_t* Wp_t = (bf16_t*)ws; ws += (long)512 * 512 * 2;
  bf16_t* Qbuf = (bf16_t*)ws; ws += (long)64 * 1024 * 16 * 2;
  bf16_t* Kbuf = (bf16_t*)ws; ws += (long)64 * 4096 * 16 * 2;
  bf16_t* Vtb  = (bf16_t*)ws; ws += (long)64 * 64 * 4096 * 2;
  bf16_t* outp = (bf16_t*)ws; ws += (long)8192 * 512 * 2;
  ws += 16384;  // slack

  cvt_f32_bf16<<<dim3(4096), 256, 0, stream>>>(x, xb, (long)8 * 4096 * 256);

  wkv_split_transpose<<<dim3(20, 8), dim3(32, 8), 0, stream>>>(Wkv, WkT, WvT);
  transpose_f32_bf16<<<dim3(4, 8),   dim3(32, 8), 0, stream>>>(Wq, Wq_t, 256, 128);
  transpose_f32_bf16<<<dim3(16, 16), dim3(32, 8), 0, stream>>>(Wp, Wp_t, 512, 512);

  // fused K/V/Q projection (replaces gemm<0>, gemm<3>, gemm<1>)
  qkv_fused<<<dim3(1536), 512, 0, stream>>>(xb, WkT,
      bkv, g_kv, b_kv, m_kv, v_kv, bq, g_q, b_q, m_q, v_q,
      Kbuf, Vtb, Qbuf);

  attn_kernel<<<dim3(1024), 256, 0, stream>>>(Qbuf, Kbuf, Vtb, outp);

  // fused output projection (replaces gemm<2>)
  proj_fused<<<dim3(256), 512, 0, stream>>>(outp, Wp_t, bp, g_p, b_p, m_p, v_p, (float*)d_out);
}

// Round 8
// 208.945 us; speedup vs baseline: 1.5495x; 1.0227x over previous
//
#include <hip/hip_runtime.h>

typedef __bf16 bf16_t;
typedef __bf16 bf16x4 __attribute__((ext_vector_type(4)));
typedef __bf16 bf16x8 __attribute__((ext_vector_type(8)));
typedef short s16x4 __attribute__((ext_vector_type(4)));
typedef float f32x4 __attribute__((ext_vector_type(4)));

#define BN_EPS 1e-3f

#define GLOAD_LDS16(g, l) \
  __builtin_amdgcn_global_load_lds((const __attribute__((address_space(1))) void*)(g), \
                                   (__attribute__((address_space(3))) void*)(l), 16, 0, 0)

// =============== prep: cvt + all 3 weight transposes in ONE launch ===============
// R8: kernel-count 7 -> 4. Unaccounted ~40-50 us in the total (sum of visible dispatches
// < dur_us) is consistent with ~7 us/launch serialization gaps. Bodies transplanted
// verbatim from the verified cvt_f32_bf16 / wkv_split_transpose / transpose_f32_bf16.
// Grid 4544 = [0,4096) cvt | [4096,4256) Wkv split 20x8 | [4256,4288) Wq 4x8 | rest Wp 16x16.
__global__ __launch_bounds__(256) void prep(
    const float* __restrict__ x, bf16_t* __restrict__ xb,
    const float* __restrict__ Wkv, bf16_t* __restrict__ outK, bf16_t* __restrict__ outV,
    const float* __restrict__ Wq, bf16_t* __restrict__ Wq_t,
    const float* __restrict__ Wp, bf16_t* __restrict__ Wp_t)
{
  __shared__ bf16_t t[32][33];
  const int id = blockIdx.x;
  if (id < 4096) {
    long i = ((long)id * 256 + threadIdx.x) * 8;
    f32x4 a = *(const f32x4*)(x + i);
    f32x4 b = *(const f32x4*)(x + i + 4);
    bf16x8 o;
    o[0] = (bf16_t)a[0]; o[1] = (bf16_t)a[1]; o[2] = (bf16_t)a[2]; o[3] = (bf16_t)a[3];
    o[4] = (bf16_t)b[0]; o[5] = (bf16_t)b[1]; o[6] = (bf16_t)b[2]; o[7] = (bf16_t)b[3];
    *(bf16x8*)(xb + i) = o;
    return;
  }
  const int tx = threadIdx.x & 31, ty = threadIdx.x >> 5;
  if (id < 4256) {                       // Wkv split-transpose [256][640]
    int id2 = id - 4096;
    int bx = (id2 % 20) * 32, by = (id2 / 20) * 32;
#pragma unroll
    for (int i = 0; i < 32; i += 8)
      t[ty + i][tx] = (bf16_t)Wkv[(long)(by + ty + i) * 640 + (bx + tx)];
    __syncthreads();
#pragma unroll
    for (int i = 0; i < 32; i += 8) {
      int c = bx + ty + i;
      int h = c / 80, r80 = c - h * 80;
      bf16_t v = t[tx][ty + i];
      if (r80 < 16)
        outK[(long)(h * 16 + r80) * 256 + (by + tx)] = v;
      else
        outV[(long)(h * 64 + (r80 - 16)) * 256 + (by + tx)] = v;
    }
  } else if (id < 4288) {                // Wq transpose: fp32 [256][128] -> [128][256]
    int id3 = id - 4256;
    int bx = (id3 & 3) * 32, by = (id3 >> 2) * 32;
#pragma unroll
    for (int i = 0; i < 32; i += 8)
      t[ty + i][tx] = (bf16_t)Wq[(long)(by + ty + i) * 128 + (bx + tx)];
    __syncthreads();
#pragma unroll
    for (int i = 0; i < 32; i += 8)
      Wq_t[(long)(bx + ty + i) * 256 + (by + tx)] = t[tx][ty + i];
  } else {                               // Wp transpose: fp32 [512][512] -> [512][512]
    int id4 = id - 4288;
    int bx = (id4 & 15) * 32, by = (id4 >> 4) * 32;
#pragma unroll
    for (int i = 0; i < 32; i += 8)
      t[ty + i][tx] = (bf16_t)Wp[(long)(by + ty + i) * 512 + (bx + tx)];
    __syncthreads();
#pragma unroll
    for (int i = 0; i < 32; i += 8)
      Wp_t[(long)(bx + ty + i) * 512 + (by + tx)] = t[tx][ty + i];
  }
}

// =============== fused QKV projection GEMM: x[32768,256] @ Wf[768,256]^T ===============
// (R6, unchanged)
__global__ __launch_bounds__(512, 1) void qkv_fused(
    const bf16_t* __restrict__ xb, const bf16_t* __restrict__ Wf,
    const float* __restrict__ bkv, const float* __restrict__ g_kv,
    const float* __restrict__ b_kv, const float* __restrict__ m_kv,
    const float* __restrict__ v_kv,
    const float* __restrict__ bq, const float* __restrict__ g_q,
    const float* __restrict__ b_q, const float* __restrict__ m_q,
    const float* __restrict__ v_q,
    bf16_t* __restrict__ Kbuf, bf16_t* __restrict__ Vtb, bf16_t* __restrict__ Qbuf)
{
  __shared__ __align__(16) char Xs[65536];   // [128 rows][256 k] bf16, swizzled units
  __shared__ __align__(16) char Ws[65536];   // [128 rows][256 k] bf16, swizzled units

  const int tid = threadIdx.x;
  const int lane = tid & 63, w = tid >> 6;        // 8 waves
  const int quad = lane >> 4, l15 = lane & 15;
  const int wm = w >> 2, wn = w & 3;              // wave grid 2x4

  const int id = blockIdx.x;
  const int xcd = id & 7, slot = id >> 3;         // slot 0..191
  const int sd6 = slot / 6;
  const int mt = xcd * 32 + sd6;                  // 0..255 (contiguous per XCD)
  const int nt = slot - sd6 * 6;                  // 0..5
  const int blockM = mt * 128, blockN = nt * 128;

  {
    const int r_lo = w * 2 + (lane >> 5);                 // row within 16-row round
    const int soff = ((lane & 31) ^ (r_lo & 7)) << 4;     // swizzled source byte in row
#pragma unroll
    for (int rnd = 0; rnd < 8; rnd++) {
      const int row = rnd * 16 + r_lo;
      GLOAD_LDS16((const char*)xb + (long)(blockM + row) * 512 + soff,
                  &Xs[rnd * 8192 + w * 1024]);
      GLOAD_LDS16((const char*)Wf + (long)(blockN + row) * 512 + soff,
                  &Ws[rnd * 8192 + w * 1024]);
    }
  }
  __syncthreads();

  const int sw = l15 & 7;
  f32x4 acc[4][2] = {};
#pragma unroll
  for (int ks = 0; ks < 8; ks++) {
    const int u = ks * 4 + quad;
    const int su = (u ^ sw) << 4;
    bf16x8 af[4];
#pragma unroll
    for (int mi = 0; mi < 4; mi++)
      af[mi] = *(const bf16x8*)(&Xs[(wm * 64 + mi * 16 + l15) * 512 + su]);
    bf16x8 bf_[2];
#pragma unroll
    for (int ni = 0; ni < 2; ni++)
      bf_[ni] = *(const bf16x8*)(&Ws[(wn * 32 + ni * 16 + l15) * 512 + su]);
#pragma unroll
    for (int mi = 0; mi < 4; mi++)
#pragma unroll
      for (int ni = 0; ni < 2; ni++)
        acc[mi][ni] = __builtin_amdgcn_mfma_f32_16x16x32_bf16(af[mi], bf_[ni], acc[mi][ni], 0, 0, 0);
  }

#pragma unroll
  for (int ni = 0; ni < 2; ni++) {
    const int nfbase = blockN + wn * 32 + ni * 16;
    const int col = nfbase + l15;
    float s, t, bia;
    if (nfbase < 128) {            // K channels
      int cp = (col >> 4) * 80 + (col & 15);
      s = g_kv[cp] / sqrtf(v_kv[cp] + BN_EPS);
      t = b_kv[cp] - m_kv[cp] * s;
      bia = bkv[cp];
      int h = col >> 4, d = col & 15;
#pragma unroll
      for (int mi = 0; mi < 4; mi++)
#pragma unroll
        for (int r = 0; r < 4; r++) {
          int grow = blockM + wm * 64 + mi * 16 + quad * 4 + r;
          int b = grow >> 12, seq = grow & 4095;
          float y = (acc[mi][ni][r] + bia) * s + t;
          Kbuf[((long)((b * 8 + h) * 4096 + seq)) * 16 + d] = (bf16_t)y;
        }
    } else if (nfbase < 640) {     // V channels -> interleaved Vt
      int ch = col - 128;
      int cp = (ch >> 6) * 80 + 16 + (ch & 63);
      s = g_kv[cp] / sqrtf(v_kv[cp] + BN_EPS);
      t = b_kv[cp] - m_kv[cp] * s;
      bia = bkv[cp];
      int h2 = ch >> 6, dv = ch & 63;
#pragma unroll
      for (int mi = 0; mi < 4; mi++)
#pragma unroll
        for (int r = 0; r < 4; r++) {
          int grow = blockM + wm * 64 + mi * 16 + quad * 4 + r;
          int b = grow >> 12, seq = grow & 4095;
          int kb = seq >> 5, s32 = seq & 31;
          int qd = (s32 & 15) >> 2, j = (s32 >> 4) * 4 + (s32 & 3);
          float y = (acc[mi][ni][r] + bia) * s + t;
          Vtb[(((long)(b * 8 + h2)) << 18) + (kb << 11) + (qd << 9) + (dv << 3) + j] = (bf16_t)y;
        }
    } else {                        // Q channels (strided-subsampled rows only)
      int qc = col - 640;
      s = g_q[qc] / sqrtf(v_q[qc] + BN_EPS);
      t = b_q[qc] - m_q[qc] * s;
      bia = bq[qc];
      int h = qc >> 4, d = qc & 15;
#pragma unroll
      for (int mi = 0; mi < 4; mi++) {
        if ((((blockM + wm * 64 + mi * 16) >> 6) & 1) != 0) continue;
#pragma unroll
        for (int r = 0; r < 4; r += 2) {
          int grow = blockM + wm * 64 + mi * 16 + quad * 4 + r;
          int b = grow >> 12, seq = grow & 4095;
          int qp = ((seq >> 7) << 5) + ((seq & 63) >> 1);
          float y = (acc[mi][ni][r] + bia) * s + t;
          Qbuf[((long)((b * 8 + h) * 1024 + qp)) * 16 + d] = (bf16_t)(y * 0.36067376f);
        }
      }
    }
  }
}

// =============== fused output projection: outp[8192,512] @ WpT[512,512]^T + BN ===============
// (R7, unchanged)
__global__ __launch_bounds__(512, 1) void proj_fused(
    const bf16_t* __restrict__ A, const bf16_t* __restrict__ Wt,
    const float* __restrict__ bias, const float* __restrict__ gamma,
    const float* __restrict__ beta, const float* __restrict__ mean,
    const float* __restrict__ var, float* __restrict__ outf)
{
  __shared__ __align__(16) char Xs[65536];
  __shared__ __align__(16) char Wl[65536];

  const int tid = threadIdx.x;
  const int lane = tid & 63, w = tid >> 6;
  const int quad = lane >> 4, l15 = lane & 15;
  const int wm = w >> 2, wn = w & 3;

  const int id = blockIdx.x;
  const int xcd = id & 7, slot = id >> 3;
  const int mt = xcd * 8 + (slot >> 2);
  const int nt = slot & 3;
  const int blockM = mt * 128, blockN = nt * 128;

  const int r_lo = w * 2 + (lane >> 5);
  const int soff = ((lane & 31) ^ (r_lo & 7)) << 4;
  const int sw = l15 & 7;
  f32x4 acc[4][2] = {};

#pragma unroll
  for (int kc = 0; kc < 2; kc++) {
    if (kc) __syncthreads();
#pragma unroll
    for (int rnd = 0; rnd < 8; rnd++) {
      const int row = rnd * 16 + r_lo;
      GLOAD_LDS16((const char*)A  + (long)(blockM + row) * 1024 + kc * 512 + soff,
                  &Xs[rnd * 8192 + w * 1024]);
      GLOAD_LDS16((const char*)Wt + (long)(blockN + row) * 1024 + kc * 512 + soff,
                  &Wl[rnd * 8192 + w * 1024]);
    }
    __syncthreads();

#pragma unroll
    for (int ks = 0; ks < 8; ks++) {
      const int u = ks * 4 + quad;
      const int su = (u ^ sw) << 4;
      bf16x8 af[4];
#pragma unroll
      for (int mi = 0; mi < 4; mi++)
        af[mi] = *(const bf16x8*)(&Xs[(wm * 64 + mi * 16 + l15) * 512 + su]);
      bf16x8 bw[2];
#pragma unroll
      for (int ni = 0; ni < 2; ni++)
        bw[ni] = *(const bf16x8*)(&Wl[(wn * 32 + ni * 16 + l15) * 512 + su]);
#pragma unroll
      for (int mi = 0; mi < 4; mi++)
#pragma unroll
        for (int ni = 0; ni < 2; ni++)
          acc[mi][ni] = __builtin_amdgcn_mfma_f32_16x16x32_bf16(af[mi], bw[ni], acc[mi][ni], 0, 0, 0);
    }
  }

#pragma unroll
  for (int ni = 0; ni < 2; ni++) {
    int col = blockN + wn * 32 + ni * 16 + l15;
    float s = gamma[col] / sqrtf(var[col] + BN_EPS);
    float t = beta[col] - mean[col] * s;
    float bia = bias[col];
#pragma unroll
    for (int mi = 0; mi < 4; mi++)
#pragma unroll
      for (int r = 0; r < 4; r++) {
        int grow = blockM + wm * 64 + mi * 16 + quad * 4 + r;
        float y = (acc[mi][ni][r] + bia) * s + t;
        outf[(long)grow * 512 + col] = y;
      }
  }
}

// ---------------- flash attention: 32 q/wave, all-x32 MFMA, depth-3 counted vmcnt ----------------
// R8. Pipe accounting of R7's 65.6 us: LDS read pipe ~90% saturated (12 ds_read_b128 =
// 12 KB per wave per tile, INDEPENDENT of q-count; 16 waves/CU x 64 tiles x 12 KB = 12.3 MB
// at 85 B/cyc b128 rate = 145k cyc vs 157k wall). Fix: 32 q per wave (qB8[2], O[2][4],
// lpacc[2]) -- same K/V reads serve 2x the q -> LDS traffic per unit work HALVES; total
// waves halve (grid 512 = 64bh x 8qb, 2 blocks/CU = 2 waves/SIMD, keeps m114 overlap that
// R2's 1-wave/SIMD lacked). MFMA/VALU totals per q unchanged. Staging/vmcnt/barrier
// structure untouched (verified R4-R7).
__global__ __launch_bounds__(256, 2) void attn_kernel(
    const bf16_t* __restrict__ Q, const bf16_t* __restrict__ K,
    const bf16_t* __restrict__ Vt, bf16_t* __restrict__ outp)
{
  const int tid = threadIdx.x;
  const int lane = tid & 63, w = tid >> 6;                // 4 waves
  const int quad = lane >> 4, l15 = lane & 15;
  const int bh = blockIdx.x & 63, qb = blockIdx.x >> 6;   // qb 0..7
  const int b = bh >> 3, h = bh & 7;
  const bf16_t* Qp = Q + (long)bh * 1024 * 16;
  const char* Kg = (const char*)(K + (long)bh * 4096 * 16);     // [key][16d], 32 B/row
  const char* Vg = (const char*)(Vt + ((long)bh << 18));        // interleaved, 512 KB/bh

  __shared__ __align__(16) char Kl[4][2048];
  __shared__ __align__(16) char Vl[4][8192];

  const int q0 = qb * 128 + w * 32;
  // Q x32 B-frags: lane(quad,l15): k=quad*8+j -> d (quads 0,1 real, quads 2,3 zero)
  bf16x8 qB8[2];
#pragma unroll
  for (int g = 0; g < 2; g++) {
    bf16x8 qv = *(const bf16x8*)(Qp + (long)(q0 + g * 16 + l15) * 16 + (quad & 1) * 8);
    bf16x8 zq = {};
    qB8[g] = (quad < 2) ? qv : zq;
  }

  f32x4 O[2][4] = {};        // [qgroup][dv tile]: lane holds (q=l15, dv=dt*16+quad*4+r)
  f32x4 lpacc[2] = {};       // ones-MFMA: every row = sum_k P[k][q=l15]
  const f32x4 zf = {0.f, 0.f, 0.f, 0.f};

  bf16x8 ones8;
#pragma unroll
  for (int i = 0; i < 8; i++) ones8[i] = (bf16_t)1.f;

  const char* vsrc = Vg + (long)lane * 16;
  const char* ksrc = Kg + (long)lane * 32 + (w - 2) * 16;

  auto stage = [&](int t, int buf) {
    if (w < 2) {
#pragma unroll
      for (int c = 0; c < 2; c++)
        GLOAD_LDS16(vsrc + (long)t * 8192 + (w * 2 + c) * 1024, &Vl[buf][(w * 2 + c) * 1024]);
    } else {
#pragma unroll
      for (int c = 0; c < 2; c++)
        GLOAD_LDS16(vsrc + (long)t * 8192 + ((w - 2) * 2 + 4 + c) * 1024,
                    &Vl[buf][((w - 2) * 2 + 4 + c) * 1024]);
      GLOAD_LDS16(ksrc + (long)t * 2048, &Kl[buf][(w - 2) * 1024]);
    }
  };

  const int krow_off = (quad & 1) * 1024;

  auto compute = [&](int buf) {
#pragma unroll
    for (int kh = 0; kh < 2; kh++) {
      bf16x8 k0 = *(const bf16x8*)(&Kl[buf][krow_off + (kh * 32 + l15) * 16]);
      bf16x8 k1 = *(const bf16x8*)(&Kl[buf][krow_off + (kh * 32 + 16 + l15) * 16]);
      bf16x8 vA[4];
#pragma unroll
      for (int dt = 0; dt < 4; dt++)
        vA[dt] = *(const bf16x8*)(&Vl[buf][kh * 4096 + quad * 1024 + (dt * 16 + l15) * 16]);
#pragma unroll
      for (int g = 0; g < 2; g++) {
        f32x4 S0 = __builtin_amdgcn_mfma_f32_16x16x32_bf16(k0, qB8[g], zf, 0, 0, 0);
        f32x4 S1 = __builtin_amdgcn_mfma_f32_16x16x32_bf16(k1, qB8[g], zf, 0, 0, 0);
        bf16x8 pb;
        pb[0] = (bf16_t)__builtin_amdgcn_exp2f(S0[0]);
        pb[1] = (bf16_t)__builtin_amdgcn_exp2f(S0[1]);
        pb[2] = (bf16_t)__builtin_amdgcn_exp2f(S0[2]);
        pb[3] = (bf16_t)__builtin_amdgcn_exp2f(S0[3]);
        pb[4] = (bf16_t)__builtin_amdgcn_exp2f(S1[0]);
        pb[5] = (bf16_t)__builtin_amdgcn_exp2f(S1[1]);
        pb[6] = (bf16_t)__builtin_amdgcn_exp2f(S1[2]);
        pb[7] = (bf16_t)__builtin_amdgcn_exp2f(S1[3]);
        lpacc[g] = __builtin_amdgcn_mfma_f32_16x16x32_bf16(ones8, pb, lpacc[g], 0, 0, 0);
#pragma unroll
        for (int dt = 0; dt < 4; dt++)
          O[g][dt] = __builtin_amdgcn_mfma_f32_16x16x32_bf16(vA[dt], pb, O[g][dt], 0, 0, 0);
      }
    }
  };

  stage(0, 0);
  stage(1, 1);
  stage(2, 2);
#pragma unroll 4
  for (int t = 0; t < 64; t++) {
    if (t + 2 < 64) {              // tiles t+1, t+2 may stay in flight
      if (w < 2) asm volatile("s_waitcnt vmcnt(4)" ::: "memory");
      else       asm volatile("s_waitcnt vmcnt(6)" ::: "memory");
    } else if (t + 1 < 64) {
      if (w < 2) asm volatile("s_waitcnt vmcnt(2)" ::: "memory");
      else       asm volatile("s_waitcnt vmcnt(3)" ::: "memory");
    } else {
      asm volatile("s_waitcnt vmcnt(0)" ::: "memory");
    }
    __builtin_amdgcn_s_barrier();
    __builtin_amdgcn_sched_barrier(0);
    if (t + 3 < 64) stage(t + 3, (t + 3) & 3);
    compute(t & 3);
  }

#pragma unroll
  for (int g = 0; g < 2; g++) {
    float rl = __builtin_amdgcn_rcpf(lpacc[g][0]);
    int q = q0 + g * 16 + l15;
    long colq = q & 511;
    long rowbase = (long)b * 1024 + (long)h * 128 + (q >> 9);
#pragma unroll
    for (int dt = 0; dt < 4; dt++) {
#pragma unroll
      for (int r = 0; r < 4; r++) {
        int dv = dt * 16 + quad * 4 + r;
        float val = O[g][dt][r] * rl;
        float hs = val * fminf(fmaxf(val + 3.f, 0.f), 6.f) * (1.f / 6.f);
        outp[(rowbase + (long)dv * 2) * 512 + colq] = (bf16_t)hs;
      }
    }
  }
}

extern "C" void kernel_launch(void* const* d_in, const int* in_sizes, int n_in,
                              void* d_out, int out_size, void* d_ws, size_t ws_size,
                              hipStream_t stream)
{
  const float* x    = (const float*)d_in[0];
  const float* Wkv  = (const float*)d_in[1];
  const float* bkv  = (const float*)d_in[2];
  const float* g_kv = (const float*)d_in[3];
  const float* b_kv = (const float*)d_in[4];
  const float* m_kv = (const float*)d_in[5];
  const float* v_kv = (const float*)d_in[6];
  const float* Wq   = (const float*)d_in[7];
  const float* bq   = (const float*)d_in[8];
  const float* g_q  = (const float*)d_in[9];
  const float* b_q  = (const float*)d_in[10];
  const float* m_q  = (const float*)d_in[11];
  const float* v_q  = (const float*)d_in[12];
  const float* Wp   = (const float*)d_in[13];
  const float* bp   = (const float*)d_in[14];
  const float* g_p  = (const float*)d_in[15];
  const float* b_p  = (const float*)d_in[16];
  const float* m_p  = (const float*)d_in[17];
  const float* v_p  = (const float*)d_in[18];

  char* ws = (char*)d_ws;
  bf16_t* xb   = (bf16_t*)ws; ws += (long)8 * 4096 * 256 * 2;
  bf16_t* WkT  = (bf16_t*)ws; ws += (long)128 * 256 * 2;   // | contiguous: Wf[768][256]
  bf16_t* WvT  = (bf16_t*)ws; ws += (long)512 * 256 * 2;   // |
  bf16_t* Wq_t = (bf16_t*)ws; ws += (long)128 * 256 * 2;   // |
  bf16_t* Wp_t = (bf16_t*)ws; ws += (long)512 * 512 * 2;
  bf16_t* Qbuf = (bf16_t*)ws; ws += (long)64 * 1024 * 16 * 2;
  bf16_t* Kbuf = (bf16_t*)ws; ws += (long)64 * 4096 * 16 * 2;
  bf16_t* Vtb  = (bf16_t*)ws; ws += (long)64 * 64 * 4096 * 2;
  bf16_t* outp = (bf16_t*)ws; ws += (long)8192 * 512 * 2;
  ws += 16384;  // slack

  // cvt + all weight transposes in one launch
  prep<<<dim3(4544), 256, 0, stream>>>(x, xb, Wkv, WkT, WvT, Wq, Wq_t, Wp, Wp_t);

  // fused K/V/Q projection
  qkv_fused<<<dim3(1536), 512, 0, stream>>>(xb, WkT,
      bkv, g_kv, b_kv, m_kv, v_kv, bq, g_q, b_q, m_q, v_q,
      Kbuf, Vtb, Qbuf);

  attn_kernel<<<dim3(512), 256, 0, stream>>>(Qbuf, Kbuf, Vtb, outp);

  // fused output projection
  proj_fused<<<dim3(256), 512, 0, stream>>>(outp, Wp_t, bp, g_p, b_p, m_p, v_p, (float*)d_out);
}